// Round 6
// baseline (1097.758 us; speedup 1.0000x reference)
//
#include <hip/hip_runtime.h>
#include <math.h>

// Problem constants (fixed instance)
#define B_      512
#define T_      128
#define CIN_    64
#define H_      256
#define COUT_   64
#define OUT_T_  32
#define NB_     16            // batch rows per scan workgroup
#define NSTEP_  (T_ - 1)      // 127
#define HWIN_   (T_ - OUT_T_) // 96: first kept time index

#define WL_SCALE 1024.0f      // keep Wl out of f16-denormal range (MFMA flush risk)
#define WL_INV   0.0009765625f

typedef _Float16 half8  __attribute__((ext_vector_type(8)));
typedef float    floatx4 __attribute__((ext_vector_type(4)));

// tanh(x) = 1 - 2/(exp(2x)+1): saturates correctly at +/-inf of exp
__device__ __forceinline__ float tanh_fast(float x){
  float e = __expf(2.0f * x);
  return 1.0f - 2.0f * __builtin_amdgcn_rcpf(e + 1.0f);
}
// sigmoid(x) = 1/(1+exp(-x))
__device__ __forceinline__ float sigm_fast(float x){
  return __builtin_amdgcn_rcpf(1.0f + __expf(-x));
}

// Pack W[K][N] (f32 row-major) into fragment-linear f16 hi + scaled lo residual:
// P[((k>>5)*N + n)*32 + (k&31)]; a wave's B-fragment load (lane l reads 8
// contiguous f16 at k-offset 8*(l>>4), col n0+(l&15)) is one 16B load.
// Pl holds (W - Wh) * 1024 so residuals stay in f16-normal range.
__global__ void pack_kernel(const float* __restrict__ W, _Float16* __restrict__ Ph,
                            _Float16* __restrict__ Pl, int K, int N){
  int i = blockIdx.x * blockDim.x + threadIdx.x;
  if (i >= K * N) return;
  int k = i / N, n = i - k * N;
  float w = W[i];
  _Float16 h = (_Float16)w;
  int idx = ((k >> 5) * N + n) * 32 + (k & 31);
  Ph[idx] = h;
  Pl[idx] = (_Float16)((w - (float)h) * WL_SCALE);
}

// ---------------- scan kernel: 32 WGs x 256 threads (4 waves) ----------------
// 1 wave/SIMD, __launch_bounds__(256,1): 512-reg unified VGPR+AGPR budget so
// the 256-reg hi-weight set (each wave owns 64 cols of BOTH Wf,Wg) is truly
// resident (R5's 8-wave/256-budget version got remat'd to L2 streams:
// VGPR_Count=128). asm-opaque after load blocks rematerialization.
// R3 numerics (absmax 1.0): per step
//   uF/uG   += dzh@Wh + dzl@Wh        (main; hi-weights resident)
//   uCF/uCG += dzh@(Wl*1024)          (weight-residual correction, Wl from L2)
//   u = uF + uCF/1024 + b ; dz = f*dt + g*sqdt*eps, split hi/lo (22-bit)
// ONE barrier per step, double-buffered dzh/dzl tiles.
__global__ __launch_bounds__(256, 1) void scan_kernel(
    const float* __restrict__ times,
    const float* __restrict__ coeffs,
    const float* __restrict__ noise,
    const float* __restrict__ W_init,
    const float* __restrict__ b_init,
    const float* __restrict__ bf,
    const float* __restrict__ bg,
    const _Float16* __restrict__ WfPh,
    const _Float16* __restrict__ WfPl,
    const _Float16* __restrict__ WgPh,
    const _Float16* __restrict__ WgPl,
    _Float16* __restrict__ zhist)
{
  __shared__ __align__(16) _Float16 zs[2][NB_ * H_]; // 16 KB, swizzled, dbuf (dzh)
  __shared__ __align__(16) _Float16 zl[2][NB_ * H_]; // 16 KB, swizzled, dbuf (dzl)
  __shared__ float x0_lds[NB_ * CIN_];               // 4 KB
  __shared__ float z0f[NB_ * H_];                    // 16 KB
  __shared__ float diffs[128];
  __shared__ float dtsh[2];

  const int tid  = threadIdx.x;
  const int lane = tid & 63;
  const int wv   = tid >> 6;    // wave 0..3
  const int lo   = lane & 15;
  const int hi   = lane >> 4;   // 0..3
  const int b0   = blockIdx.x * NB_;

  if (tid < 127) diffs[tid] = times[tid + 1] - times[tid];
  if (tid == 127) diffs[127] = 3.4e38f;

  // Resident hi-weight fragments: 64 cols per wave for F and G = 256 regs.
  half8 wfh[4][8], wgh[4][8];
  #pragma unroll
  for (int t = 0; t < 4; ++t){
    int n0 = 64*wv + 16*t + lo;
    #pragma unroll
    for (int kt = 0; kt < 8; ++kt){
      wfh[t][kt] = *(const half8*)(WfPh + (kt*H_ + n0)*32 + 8*hi);
      wgh[t][kt] = *(const half8*)(WgPh + (kt*H_ + n0)*32 + 8*hi);
      // Opaque: value now unknowable => cannot be rematerialized in-loop.
      asm volatile("" : "+v"(wfh[t][kt]));
      asm volatile("" : "+v"(wgh[t][kt]));
    }
  }
  float bfv[4], bgv[4];
  #pragma unroll
  for (int t = 0; t < 4; ++t){
    bfv[t] = bf[64*wv + 16*t + lo];
    bgv[t] = bg[64*wv + 16*t + lo];
  }

  for (int i = tid; i < NB_ * CIN_; i += 256)
    x0_lds[i] = coeffs[(size_t)(b0 + (i >> 6)) * (T_ * CIN_) + (i & 63)];
  __syncthreads();

  if (tid < 64){
    float m = fminf(diffs[tid], diffs[tid + 64]);
    #pragma unroll
    for (int o = 32; o; o >>= 1) m = fminf(m, __shfl_down(m, o, 64));
    if (tid == 0){
      float dt = fmaxf(m, 0.001f);
      dtsh[0] = dt; dtsh[1] = sqrtf(dt);
    }
  }

  // z0 = x0 @ W_init + b_init (exact f32, VALU). 256 threads: 16 cols each.
  {
    int r = tid & 15, c0 = (tid >> 4) * 16;   // tid>>4 in 0..15
    float acc[16];
    #pragma unroll
    for (int j = 0; j < 16; ++j) acc[j] = b_init[c0 + j];
    for (int k = 0; k < CIN_; ++k){
      float x = x0_lds[r * CIN_ + k];
      const float* wrow = W_init + k * H_ + c0;
      #pragma unroll
      for (int j = 0; j < 16; ++j) acc[j] += x * wrow[j];
    }
    #pragma unroll
    for (int j = 0; j < 16; ++j) z0f[r * H_ + c0 + j] = acc[j];
  }
  __syncthreads();

  const float dt = dtsh[0], sqdt = dtsh[1];

  // f32 master z (C/D layout: col = lane&15 + 16*t + 64*wv, row = 4*hi+rg)
  float zreg[4][4];
  #pragma unroll
  for (int t = 0; t < 4; ++t){
    int col = 64*wv + 16*t + lo;
    #pragma unroll
    for (int rg = 0; rg < 4; ++rg)
      zreg[t][rg] = z0f[(hi*4 + rg) * H_ + col];
  }
  // Seed swizzled z0 hi/lo tiles into buffer 0
  for (int i = tid; i < NB_ * H_; i += 256){
    int rr = i >> 8;
    float zv = z0f[i];
    _Float16 zh = (_Float16)zv;
    int idx = i ^ ((rr & 7) << 3);
    zs[0][idx] = zh;
    zl[0][idx] = (_Float16)(zv - (float)zh);
  }
  __syncthreads();

  const int n0a = 64*wv + lo;
  const int eb0 = (b0 + hi*4) * H_ + 64*wv + lo;
  const size_t zh0 = (size_t)(b0 + hi*4) * (OUT_T_ * H_) + 64*wv + lo;

  // Per-lane LDS offsets (element units within one buffer)
  int aoff[8];
  #pragma unroll
  for (int kt = 0; kt < 8; ++kt)
    aoff[kt] = (lo*H_ + kt*32 + hi*8) ^ ((lo & 7) << 3);
  int woff[4][4];
  #pragma unroll
  for (int t = 0; t < 4; ++t)
    #pragma unroll
    for (int rg = 0; rg < 4; ++rg){
      int row = hi*4 + rg;
      woff[t][rg] = (row * H_ + 64*wv + 16*t + lo) ^ ((row & 7) << 3);
    }

  // u0 = z0@W as 3-term: z0h@Wh + z0l@Wh (main) ; z0h@Wl*1024 (corr)
  floatx4 uF[4], uG[4], uCF[4], uCG[4];
  #pragma unroll
  for (int t = 0; t < 4; ++t){
    uF[t] = (floatx4){0.f,0.f,0.f,0.f};
    uG[t] = uF[t]; uCF[t] = uF[t]; uCG[t] = uF[t];
  }
  #pragma unroll
  for (int kt = 0; kt < 8; ++kt){
    half8 ah = *(const half8*)&zs[0][aoff[kt]];
    half8 al = *(const half8*)&zl[0][aoff[kt]];
    #pragma unroll
    for (int t = 0; t < 4; ++t){
      half8 flw = *(const half8*)(WfPl + (kt*H_ + n0a + 16*t)*32 + 8*hi);
      half8 glw = *(const half8*)(WgPl + (kt*H_ + n0a + 16*t)*32 + 8*hi);
      uF[t]  = __builtin_amdgcn_mfma_f32_16x16x32_f16(ah, wfh[t][kt], uF[t], 0,0,0);
      uF[t]  = __builtin_amdgcn_mfma_f32_16x16x32_f16(al, wfh[t][kt], uF[t], 0,0,0);
      uCF[t] = __builtin_amdgcn_mfma_f32_16x16x32_f16(ah, flw,        uCF[t],0,0,0);
      uG[t]  = __builtin_amdgcn_mfma_f32_16x16x32_f16(ah, wgh[t][kt], uG[t], 0,0,0);
      uG[t]  = __builtin_amdgcn_mfma_f32_16x16x32_f16(al, wgh[t][kt], uG[t], 0,0,0);
      uCG[t] = __builtin_amdgcn_mfma_f32_16x16x32_f16(ah, glw,        uCG[t],0,0,0);
    }
  }

  // Prologue eps (s=0)
  float eps[4][4];
  #pragma unroll
  for (int t = 0; t < 4; ++t)
    #pragma unroll
    for (int rg = 0; rg < 4; ++rg)
      eps[t][rg] = noise[eb0 + rg*H_ + t*16];

  // Protect buffer 0 from s=0 overwrite until all waves consumed seed reads
  __syncthreads();

  unsigned int wlo = 0;   // opaque 0: blocks LICM of the per-step Wl streams

  // ---------------- main sequential scan: ONE barrier per step -------------
  for (int s = 0; s < NSTEP_; ++s){
    const int b = s & 1;

    // VALU phase: f,g,dz from u (complete from prev iter); dz split hi/lo
    _Float16 dzh[4][4], dzl[4][4];
    #pragma unroll
    for (int t = 0; t < 4; ++t)
      #pragma unroll
      for (int rg = 0; rg < 4; ++rg){
        float uf = fmaf(WL_INV, uCF[t][rg], uF[t][rg]) + bfv[t];
        float ug = fmaf(WL_INV, uCG[t][rg], uG[t][rg]) + bgv[t];
        float f = tanh_fast(uf);
        float g = sigm_fast(ug);
        float dz = fmaf(g, sqdt * eps[t][rg], f * dt);
        _Float16 dh = (_Float16)dz;
        _Float16 dl = (_Float16)(dz - (float)dh);
        dzh[t][rg] = dh; dzl[t][rg] = dl;
        zreg[t][rg] += (float)dh + (float)dl;  // master == what u tracks
      }

    // Write dz tiles into buffer b (prev iter read buffer b^1 — no race)
    #pragma unroll
    for (int t = 0; t < 4; ++t)
      #pragma unroll
      for (int rg = 0; rg < 4; ++rg){
        zs[b][woff[t][rg]] = dzh[t][rg];
        zl[b][woff[t][rg]] = dzl[t][rg];
      }

    __syncthreads();   // single barrier: dz tiles visible

    // Post-barrier: global traffic first (covered by MFMA phase)
    if (s + 1 < NSTEP_){
      const float* np_ = noise + (size_t)(s + 1) * (B_ * H_);
      #pragma unroll
      for (int t = 0; t < 4; ++t)
        #pragma unroll
        for (int rg = 0; rg < 4; ++rg)
          eps[t][rg] = np_[eb0 + rg*H_ + t*16];
    }
    if (s >= HWIN_ - 1){
      int sl = s - (HWIN_ - 1);
      #pragma unroll
      for (int t = 0; t < 4; ++t)
        #pragma unroll
        for (int rg = 0; rg < 4; ++rg)
          zhist[zh0 + (size_t)rg*(OUT_T_*H_) + sl*H_ + t*16] = (_Float16)zreg[t][rg];
    }

    if (s + 1 < NSTEP_){
      const _Float16* wflp = (const _Float16*)((const char*)WfPl + wlo);
      const _Float16* wglp = (const _Float16*)((const char*)WgPl + wlo);
      #pragma unroll
      for (int kt = 0; kt < 8; ++kt){
        half8 ah = *(const half8*)&zs[b][aoff[kt]];
        half8 al = *(const half8*)&zl[b][aoff[kt]];
        #pragma unroll
        for (int t = 0; t < 4; ++t){
          half8 flw = *(const half8*)(wflp + (kt*H_ + n0a + 16*t)*32 + 8*hi);
          half8 glw = *(const half8*)(wglp + (kt*H_ + n0a + 16*t)*32 + 8*hi);
          uF[t]  = __builtin_amdgcn_mfma_f32_16x16x32_f16(ah, wfh[t][kt], uF[t], 0,0,0);
          uF[t]  = __builtin_amdgcn_mfma_f32_16x16x32_f16(al, wfh[t][kt], uF[t], 0,0,0);
          uCF[t] = __builtin_amdgcn_mfma_f32_16x16x32_f16(ah, flw,        uCF[t],0,0,0);
          uG[t]  = __builtin_amdgcn_mfma_f32_16x16x32_f16(ah, wgh[t][kt], uG[t], 0,0,0);
          uG[t]  = __builtin_amdgcn_mfma_f32_16x16x32_f16(al, wgh[t][kt], uG[t], 0,0,0);
          uCG[t] = __builtin_amdgcn_mfma_f32_16x16x32_f16(ah, glw,        uCG[t],0,0,0);
        }
      }
    }
    asm volatile("" : "+v"(wlo));   // keep Wl streams loop-variant (no LICM)
  }
}

// ---------------- head kernel: pred_y = relu(h@W1+b1)@W2 + b2 ----------------
__global__ __launch_bounds__(256) void head_kernel(
    const _Float16* __restrict__ zhist,
    const _Float16* __restrict__ W1P,
    const _Float16* __restrict__ W2P,
    const float* __restrict__ b1,
    const float* __restrict__ b2,
    float* __restrict__ out)
{
  __shared__ __align__(16) _Float16 hbuf[64 * H_];  // 32 KB, swizzled
  __shared__ __align__(16) _Float16 ubuf[64 * H_];  // 32 KB, swizzled

  const int tid  = threadIdx.x;
  const int lane = tid & 63;
  const int wv   = tid >> 6;   // 0..3
  const int lo   = lane & 15;
  const int hi   = lane >> 4;
  const int m0   = blockIdx.x * 64;

  for (int c = tid; c < 64 * 32; c += 256){
    int rr = c >> 5, c8 = (c & 31) * 8;
    *(half8*)&hbuf[(rr * H_ + c8) ^ ((rr & 7) << 3)] =
        *(const half8*)&zhist[(size_t)(m0 + rr) * H_ + c8];
  }

  half8 w1f[4][8];
  #pragma unroll
  for (int nt = 0; nt < 4; ++nt){
    int n0 = 64*wv + 16*nt + lo;
    #pragma unroll
    for (int kt = 0; kt < 8; ++kt)
      w1f[nt][kt] = *(const half8*)(W1P + (kt*H_ + n0)*32 + 8*hi);
  }
  half8 w2f[8];
  #pragma unroll
  for (int kt = 0; kt < 8; ++kt)
    w2f[kt] = *(const half8*)(W2P + (kt*COUT_ + 16*wv + lo)*32 + 8*hi);

  float b1v[4];
  #pragma unroll
  for (int nt = 0; nt < 4; ++nt) b1v[nt] = b1[64*wv + 16*nt + lo];
  float b2v = b2[16*wv + lo];

  __syncthreads();

  // Stage 1: U = relu(h @ W1 + b1)
  for (int mt = 0; mt < 4; ++mt){
    half8 a[8];
    #pragma unroll
    for (int kt = 0; kt < 8; ++kt)
      a[kt] = *(const half8*)&hbuf[((mt*16 + lo) * H_ + kt*32 + hi*8) ^ ((lo & 7) << 3)];
    #pragma unroll
    for (int nt = 0; nt < 4; ++nt){
      floatx4 acc = {0.f,0.f,0.f,0.f};
      #pragma unroll
      for (int kt = 0; kt < 8; ++kt)
        acc = __builtin_amdgcn_mfma_f32_16x16x32_f16(a[kt], w1f[nt][kt], acc, 0,0,0);
      #pragma unroll
      for (int rg = 0; rg < 4; ++rg){
        float u = fmaxf(acc[rg] + b1v[nt], 0.0f);
        int rr = mt*16 + hi*4 + rg;
        int cc = 64*wv + 16*nt + lo;
        ubuf[(rr * H_ + cc) ^ ((rr & 7) << 3)] = (_Float16)u;
      }
    }
  }
  __syncthreads();

  // Stage 2: out = U @ W2 + b2
  for (int mt = 0; mt < 4; ++mt){
    half8 a[8];
    #pragma unroll
    for (int kt = 0; kt < 8; ++kt)
      a[kt] = *(const half8*)&ubuf[((mt*16 + lo) * H_ + kt*32 + hi*8) ^ ((lo & 7) << 3)];
    floatx4 acc = {0.f,0.f,0.f,0.f};
    #pragma unroll
    for (int kt = 0; kt < 8; ++kt)
      acc = __builtin_amdgcn_mfma_f32_16x16x32_f16(a[kt], w2f[kt], acc, 0,0,0);
    #pragma unroll
    for (int rg = 0; rg < 4; ++rg)
      out[(size_t)(m0 + mt*16 + hi*4 + rg) * COUT_ + 16*wv + lo] = acc[rg] + b2v;
  }
}

extern "C" void kernel_launch(void* const* d_in, const int* in_sizes, int n_in,
                              void* d_out, int out_size, void* d_ws, size_t ws_size,
                              hipStream_t stream) {
  const float* times  = (const float*)d_in[0];
  const float* coeffs = (const float*)d_in[1];
  const float* noise  = (const float*)d_in[2];
  const float* W_init = (const float*)d_in[3];
  const float* b_init = (const float*)d_in[4];
  const float* Wf     = (const float*)d_in[5];
  const float* bf     = (const float*)d_in[6];
  const float* Wg     = (const float*)d_in[7];
  const float* bg     = (const float*)d_in[8];
  const float* W1     = (const float*)d_in[9];
  const float* b1     = (const float*)d_in[10];
  const float* W2     = (const float*)d_in[11];
  const float* b2     = (const float*)d_in[12];

  // Workspace: zhist (8.39 MB) | 8 x 128KB packed-weight slots
  char* ws = (char*)d_ws;
  _Float16* zhist = (_Float16*)(ws);
  char* wbase = ws + 8388608;
  _Float16* WfPh = (_Float16*)(wbase + 0*131072);
  _Float16* WfPl = (_Float16*)(wbase + 1*131072);
  _Float16* WgPh = (_Float16*)(wbase + 2*131072);
  _Float16* WgPl = (_Float16*)(wbase + 3*131072);
  _Float16* W1Ph = (_Float16*)(wbase + 4*131072);
  _Float16* W1Pl = (_Float16*)(wbase + 5*131072);
  _Float16* W2Ph = (_Float16*)(wbase + 6*131072);
  _Float16* W2Pl = (_Float16*)(wbase + 7*131072);

  pack_kernel<<<(H_*H_ + 255)/256, 256, 0, stream>>>(Wf, WfPh, WfPl, H_, H_);
  pack_kernel<<<(H_*H_ + 255)/256, 256, 0, stream>>>(Wg, WgPh, WgPl, H_, H_);
  pack_kernel<<<(H_*H_ + 255)/256, 256, 0, stream>>>(W1, W1Ph, W1Pl, H_, H_);
  pack_kernel<<<(H_*COUT_ + 255)/256, 256, 0, stream>>>(W2, W2Ph, W2Pl, H_, COUT_);

  scan_kernel<<<B_ / NB_, 256, 0, stream>>>(times, coeffs, noise, W_init, b_init,
                                            bf, bg, WfPh, WfPl, WgPh, WgPl, zhist);

  head_kernel<<<(B_ * OUT_T_) / 64, 256, 0, stream>>>(zhist, W1Ph, W2Ph, b1, b2,
                                                      (float*)d_out);
}

// Round 8
// 706.162 us; speedup vs baseline: 1.5545x; 1.5545x over previous
//
#include <hip/hip_runtime.h>
#include <math.h>

// Problem constants (fixed instance)
#define B_      512
#define T_      128
#define CIN_    64
#define H_      256
#define COUT_   64
#define OUT_T_  32
#define NB_     16            // batch rows per scan workgroup
#define NSTEP_  (T_ - 1)      // 127
#define HWIN_   (T_ - OUT_T_) // 96: first kept time index

#define WL_SCALE 1024.0f      // keep Wl out of f16-denormal range (MFMA flush risk)
#define WL_INV   0.0009765625f

typedef _Float16 half8  __attribute__((ext_vector_type(8)));
typedef float    floatx4 __attribute__((ext_vector_type(4)));

// tanh(x) = 1 - 2/(exp(2x)+1): saturates correctly at +/-inf of exp
__device__ __forceinline__ float tanh_fast(float x){
  float e = __expf(2.0f * x);
  return 1.0f - 2.0f * __builtin_amdgcn_rcpf(e + 1.0f);
}
// sigmoid(x) = 1/(1+exp(-x))
__device__ __forceinline__ float sigm_fast(float x){
  return __builtin_amdgcn_rcpf(1.0f + __expf(-x));
}

// Pack W[K][N] (f32 row-major) into fragment-linear f16 hi + scaled lo residual:
// P[((k>>5)*N + n)*32 + (k&31)]; a wave's B-fragment load (lane l reads 8
// contiguous f16 at k-offset 8*(l>>4), col n0+(l&15)) is one 16B load.
// Pl holds (W - Wh) * 1024 so residuals stay in f16-normal range.
__global__ void pack_kernel(const float* __restrict__ W, _Float16* __restrict__ Ph,
                            _Float16* __restrict__ Pl, int K, int N){
  int i = blockIdx.x * blockDim.x + threadIdx.x;
  if (i >= K * N) return;
  int k = i / N, n = i - k * N;
  float w = W[i];
  _Float16 h = (_Float16)w;
  int idx = ((k >> 5) * N + n) * 32 + (k & 31);
  Ph[idx] = h;
  Pl[idx] = (_Float16)((w - (float)h) * WL_SCALE);
}

// ---------------- scan kernel: 32 WGs x 512 threads (8 waves) ----------------
// {8 waves, 2/SIMD TLP, forced residency}: per-wave weight set is 128 VGPR
// (32 cols of BOTH Wf,Wg), total ~210 < 256 budget from launch_bounds(512,2).
// asm-opaque makes remat impossible (R5's allocator re-streamed weights from
// L2 every step; R6 proved the opaque forces residency but killed TLP).
// R3/R5 numerics (absmax 1.0): per step
//   uF/uG   += dzh@Wh + dzl@Wh        (main; hi-weights resident)
//   uCF/uCG += dzh@(Wl*1024)          (weight-residual correction, Wl from L2)
//   u = uF + uCF/1024 + b ; dz = f*dt + g*sqdt*eps, split hi/lo (22-bit)
// ONE barrier per step, double-buffered dzh/dzl tiles.
__global__ __launch_bounds__(512, 2) void scan_kernel(
    const float* __restrict__ times,
    const float* __restrict__ coeffs,
    const float* __restrict__ noise,
    const float* __restrict__ W_init,
    const float* __restrict__ b_init,
    const float* __restrict__ bf,
    const float* __restrict__ bg,
    const _Float16* __restrict__ WfPh,
    const _Float16* __restrict__ WfPl,
    const _Float16* __restrict__ WgPh,
    const _Float16* __restrict__ WgPl,
    _Float16* __restrict__ zhist)
{
  __shared__ __align__(16) _Float16 zs[2][NB_ * H_]; // 16 KB, swizzled, dbuf (dzh)
  __shared__ __align__(16) _Float16 zl[2][NB_ * H_]; // 16 KB, swizzled, dbuf (dzl)
  __shared__ float x0_lds[NB_ * CIN_];               // 4 KB
  __shared__ float z0f[NB_ * H_];                    // 16 KB
  __shared__ float diffs[128];
  __shared__ float dtsh[2];

  const int tid  = threadIdx.x;
  const int lane = tid & 63;
  const int wv   = tid >> 6;    // wave 0..7
  const int lo   = lane & 15;
  const int hi   = lane >> 4;   // 0..3
  const int b0   = blockIdx.x * NB_;

  if (tid < 127) diffs[tid] = times[tid + 1] - times[tid];
  if (tid == 127) diffs[127] = 3.4e38f;

  // Resident hi-weight fragments: 32 cols per wave for F and G = 128 VGPRs.
  // asm-opaque: value becomes unknowable => rematerialization impossible.
  half8 wfh[2][8], wgh[2][8];
  #pragma unroll
  for (int t2 = 0; t2 < 2; ++t2){
    int n0 = 32*wv + 16*t2 + lo;
    #pragma unroll
    for (int kt = 0; kt < 8; ++kt){
      wfh[t2][kt] = *(const half8*)(WfPh + (kt*H_ + n0)*32 + 8*hi);
      wgh[t2][kt] = *(const half8*)(WgPh + (kt*H_ + n0)*32 + 8*hi);
      asm volatile("" : "+v"(wfh[t2][kt]));
      asm volatile("" : "+v"(wgh[t2][kt]));
    }
  }
  float bfv[2], bgv[2];
  #pragma unroll
  for (int t2 = 0; t2 < 2; ++t2){
    bfv[t2] = bf[32*wv + 16*t2 + lo];
    bgv[t2] = bg[32*wv + 16*t2 + lo];
  }

  for (int i = tid; i < NB_ * CIN_; i += 512)
    x0_lds[i] = coeffs[(size_t)(b0 + (i >> 6)) * (T_ * CIN_) + (i & 63)];
  __syncthreads();

  if (tid < 64){
    float m = fminf(diffs[tid], diffs[tid + 64]);
    #pragma unroll
    for (int o = 32; o; o >>= 1) m = fminf(m, __shfl_down(m, o, 64));
    if (tid == 0){
      float dt = fmaxf(m, 0.001f);
      dtsh[0] = dt; dtsh[1] = sqrtf(dt);
    }
  }

  // z0 = x0 @ W_init + b_init (exact f32, VALU)
  {
    int r = tid & 15, c0 = (tid >> 4) * 8;   // tid>>4 in 0..31
    float acc[8];
    #pragma unroll
    for (int j = 0; j < 8; ++j) acc[j] = b_init[c0 + j];
    for (int k = 0; k < CIN_; ++k){
      float x = x0_lds[r * CIN_ + k];
      const float* wrow = W_init + k * H_ + c0;
      #pragma unroll
      for (int j = 0; j < 8; ++j) acc[j] += x * wrow[j];
    }
    #pragma unroll
    for (int j = 0; j < 8; ++j) z0f[r * H_ + c0 + j] = acc[j];
  }
  __syncthreads();

  const float dt = dtsh[0], sqdt = dtsh[1];

  // f32 master z (C/D layout: col = lane&15 + 16*t2 + 32*wv, row = 4*hi+rg)
  float zreg[2][4];
  #pragma unroll
  for (int t2 = 0; t2 < 2; ++t2){
    int col = 32*wv + 16*t2 + lo;
    #pragma unroll
    for (int rg = 0; rg < 4; ++rg)
      zreg[t2][rg] = z0f[(hi*4 + rg) * H_ + col];
  }
  // Seed swizzled z0 hi/lo tiles into buffer 0
  for (int i = tid; i < NB_ * H_; i += 512){
    int rr = i >> 8;
    float zv = z0f[i];
    _Float16 zh = (_Float16)zv;
    int idx = i ^ ((rr & 7) << 3);
    zs[0][idx] = zh;
    zl[0][idx] = (_Float16)(zv - (float)zh);
  }
  __syncthreads();

  const int n0a = 32*wv + lo;
  const int eb0 = (b0 + hi*4) * H_ + 32*wv + lo;
  const size_t zh0 = (size_t)(b0 + hi*4) * (OUT_T_ * H_) + 32*wv + lo;

  // Per-lane LDS offsets (element units within one buffer)
  int aoff[8];
  #pragma unroll
  for (int kt = 0; kt < 8; ++kt)
    aoff[kt] = (lo*H_ + kt*32 + hi*8) ^ ((lo & 7) << 3);
  int woff[2][4];
  #pragma unroll
  for (int t2 = 0; t2 < 2; ++t2)
    #pragma unroll
    for (int rg = 0; rg < 4; ++rg){
      int row = hi*4 + rg;
      woff[t2][rg] = (row * H_ + 32*wv + 16*t2 + lo) ^ ((row & 7) << 3);
    }

  // u0 = z0@W as 3-term: z0h@Wh + z0l@Wh (main) ; z0h@Wl*1024 (corr)
  floatx4 uF[2], uG[2], uCF[2], uCG[2];
  uF[0] = (floatx4){0.f,0.f,0.f,0.f}; uF[1] = uF[0];
  uG[0] = uF[0]; uG[1] = uF[0];
  uCF[0] = uF[0]; uCF[1] = uF[0]; uCG[0] = uF[0]; uCG[1] = uF[0];
  #pragma unroll
  for (int kt = 0; kt < 8; ++kt){
    half8 ah = *(const half8*)&zs[0][aoff[kt]];
    half8 al = *(const half8*)&zl[0][aoff[kt]];
    #pragma unroll
    for (int t2 = 0; t2 < 2; ++t2){
      half8 flw = *(const half8*)(WfPl + (kt*H_ + n0a + 16*t2)*32 + 8*hi);
      half8 glw = *(const half8*)(WgPl + (kt*H_ + n0a + 16*t2)*32 + 8*hi);
      uF[t2]  = __builtin_amdgcn_mfma_f32_16x16x32_f16(ah, wfh[t2][kt], uF[t2], 0,0,0);
      uF[t2]  = __builtin_amdgcn_mfma_f32_16x16x32_f16(al, wfh[t2][kt], uF[t2], 0,0,0);
      uCF[t2] = __builtin_amdgcn_mfma_f32_16x16x32_f16(ah, flw,         uCF[t2],0,0,0);
      uG[t2]  = __builtin_amdgcn_mfma_f32_16x16x32_f16(ah, wgh[t2][kt], uG[t2], 0,0,0);
      uG[t2]  = __builtin_amdgcn_mfma_f32_16x16x32_f16(al, wgh[t2][kt], uG[t2], 0,0,0);
      uCG[t2] = __builtin_amdgcn_mfma_f32_16x16x32_f16(ah, glw,         uCG[t2],0,0,0);
    }
  }

  // Prologue eps (s=0)
  float eps[2][4];
  #pragma unroll
  for (int t2 = 0; t2 < 2; ++t2)
    #pragma unroll
    for (int rg = 0; rg < 4; ++rg)
      eps[t2][rg] = noise[eb0 + rg*H_ + t2*16];

  // Protect buffer 0 from s=0 overwrite until all waves consumed seed reads
  __syncthreads();

  unsigned int wlo = 0;   // opaque 0: blocks LICM of the per-step Wl streams

  // ---------------- main sequential scan: ONE barrier per step -------------
  for (int s = 0; s < NSTEP_; ++s){
    const int b = s & 1;

    // VALU phase: f,g,dz from u (complete from prev iter); dz split hi/lo
    _Float16 dzh[2][4], dzl[2][4];
    #pragma unroll
    for (int t2 = 0; t2 < 2; ++t2)
      #pragma unroll
      for (int rg = 0; rg < 4; ++rg){
        float uf = fmaf(WL_INV, uCF[t2][rg], uF[t2][rg]) + bfv[t2];
        float ug = fmaf(WL_INV, uCG[t2][rg], uG[t2][rg]) + bgv[t2];
        float f = tanh_fast(uf);
        float g = sigm_fast(ug);
        float dz = fmaf(g, sqdt * eps[t2][rg], f * dt);
        _Float16 dh = (_Float16)dz;
        _Float16 dl = (_Float16)(dz - (float)dh);
        dzh[t2][rg] = dh; dzl[t2][rg] = dl;
        zreg[t2][rg] += (float)dh + (float)dl;  // master == what u tracks
      }

    // Write dz tiles into buffer b (prev iter read buffer b^1 — no race)
    #pragma unroll
    for (int t2 = 0; t2 < 2; ++t2)
      #pragma unroll
      for (int rg = 0; rg < 4; ++rg){
        zs[b][woff[t2][rg]] = dzh[t2][rg];
        zl[b][woff[t2][rg]] = dzl[t2][rg];
      }

    __syncthreads();   // single barrier: dz tiles visible

    // Post-barrier: global traffic first (covered by MFMA phase)
    if (s + 1 < NSTEP_){
      const float* np_ = noise + (size_t)(s + 1) * (B_ * H_);
      #pragma unroll
      for (int t2 = 0; t2 < 2; ++t2)
        #pragma unroll
        for (int rg = 0; rg < 4; ++rg)
          eps[t2][rg] = np_[eb0 + rg*H_ + t2*16];
    }
    if (s >= HWIN_ - 1){
      int sl = s - (HWIN_ - 1);
      #pragma unroll
      for (int t2 = 0; t2 < 2; ++t2)
        #pragma unroll
        for (int rg = 0; rg < 4; ++rg)
          zhist[zh0 + (size_t)rg*(OUT_T_*H_) + sl*H_ + t2*16] = (_Float16)zreg[t2][rg];
    }

    if (s + 1 < NSTEP_){
      const _Float16* wflp = (const _Float16*)((const char*)WfPl + wlo);
      const _Float16* wglp = (const _Float16*)((const char*)WgPl + wlo);
      #pragma unroll
      for (int kt = 0; kt < 8; ++kt){
        half8 ah = *(const half8*)&zs[b][aoff[kt]];
        half8 al = *(const half8*)&zl[b][aoff[kt]];
        #pragma unroll
        for (int t2 = 0; t2 < 2; ++t2){
          half8 flw = *(const half8*)(wflp + (kt*H_ + n0a + 16*t2)*32 + 8*hi);
          half8 glw = *(const half8*)(wglp + (kt*H_ + n0a + 16*t2)*32 + 8*hi);
          uF[t2]  = __builtin_amdgcn_mfma_f32_16x16x32_f16(ah, wfh[t2][kt], uF[t2], 0,0,0);
          uF[t2]  = __builtin_amdgcn_mfma_f32_16x16x32_f16(al, wfh[t2][kt], uF[t2], 0,0,0);
          uCF[t2] = __builtin_amdgcn_mfma_f32_16x16x32_f16(ah, flw,         uCF[t2],0,0,0);
          uG[t2]  = __builtin_amdgcn_mfma_f32_16x16x32_f16(ah, wgh[t2][kt], uG[t2], 0,0,0);
          uG[t2]  = __builtin_amdgcn_mfma_f32_16x16x32_f16(al, wgh[t2][kt], uG[t2], 0,0,0);
          uCG[t2] = __builtin_amdgcn_mfma_f32_16x16x32_f16(ah, glw,         uCG[t2],0,0,0);
        }
      }
    }
    asm volatile("" : "+v"(wlo));   // keep Wl streams loop-variant (no LICM)
  }
}

// ---------------- head kernel: pred_y = relu(h@W1+b1)@W2 + b2 ----------------
__global__ __launch_bounds__(256) void head_kernel(
    const _Float16* __restrict__ zhist,
    const _Float16* __restrict__ W1P,
    const _Float16* __restrict__ W2P,
    const float* __restrict__ b1,
    const float* __restrict__ b2,
    float* __restrict__ out)
{
  __shared__ __align__(16) _Float16 hbuf[64 * H_];  // 32 KB, swizzled
  __shared__ __align__(16) _Float16 ubuf[64 * H_];  // 32 KB, swizzled

  const int tid  = threadIdx.x;
  const int lane = tid & 63;
  const int wv   = tid >> 6;   // 0..3
  const int lo   = lane & 15;
  const int hi   = lane >> 4;
  const int m0   = blockIdx.x * 64;

  for (int c = tid; c < 64 * 32; c += 256){
    int rr = c >> 5, c8 = (c & 31) * 8;
    *(half8*)&hbuf[(rr * H_ + c8) ^ ((rr & 7) << 3)] =
        *(const half8*)&zhist[(size_t)(m0 + rr) * H_ + c8];
  }

  half8 w1f[4][8];
  #pragma unroll
  for (int nt = 0; nt < 4; ++nt){
    int n0 = 64*wv + 16*nt + lo;
    #pragma unroll
    for (int kt = 0; kt < 8; ++kt)
      w1f[nt][kt] = *(const half8*)(W1P + (kt*H_ + n0)*32 + 8*hi);
  }
  half8 w2f[8];
  #pragma unroll
  for (int kt = 0; kt < 8; ++kt)
    w2f[kt] = *(const half8*)(W2P + (kt*COUT_ + 16*wv + lo)*32 + 8*hi);

  float b1v[4];
  #pragma unroll
  for (int nt = 0; nt < 4; ++nt) b1v[nt] = b1[64*wv + 16*nt + lo];
  float b2v = b2[16*wv + lo];

  __syncthreads();

  // Stage 1: U = relu(h @ W1 + b1)
  for (int mt = 0; mt < 4; ++mt){
    half8 a[8];
    #pragma unroll
    for (int kt = 0; kt < 8; ++kt)
      a[kt] = *(const half8*)&hbuf[((mt*16 + lo) * H_ + kt*32 + hi*8) ^ ((lo & 7) << 3)];
    #pragma unroll
    for (int nt = 0; nt < 4; ++nt){
      floatx4 acc = {0.f,0.f,0.f,0.f};
      #pragma unroll
      for (int kt = 0; kt < 8; ++kt)
        acc = __builtin_amdgcn_mfma_f32_16x16x32_f16(a[kt], w1f[nt][kt], acc, 0,0,0);
      #pragma unroll
      for (int rg = 0; rg < 4; ++rg){
        float u = fmaxf(acc[rg] + b1v[nt], 0.0f);
        int rr = mt*16 + hi*4 + rg;
        int cc = 64*wv + 16*nt + lo;
        ubuf[(rr * H_ + cc) ^ ((rr & 7) << 3)] = (_Float16)u;
      }
    }
  }
  __syncthreads();

  // Stage 2: out = U @ W2 + b2
  for (int mt = 0; mt < 4; ++mt){
    half8 a[8];
    #pragma unroll
    for (int kt = 0; kt < 8; ++kt)
      a[kt] = *(const half8*)&ubuf[((mt*16 + lo) * H_ + kt*32 + hi*8) ^ ((lo & 7) << 3)];
    floatx4 acc = {0.f,0.f,0.f,0.f};
    #pragma unroll
    for (int kt = 0; kt < 8; ++kt)
      acc = __builtin_amdgcn_mfma_f32_16x16x32_f16(a[kt], w2f[kt], acc, 0,0,0);
    #pragma unroll
    for (int rg = 0; rg < 4; ++rg)
      out[(size_t)(m0 + mt*16 + hi*4 + rg) * COUT_ + 16*wv + lo] = acc[rg] + b2v;
  }
}

extern "C" void kernel_launch(void* const* d_in, const int* in_sizes, int n_in,
                              void* d_out, int out_size, void* d_ws, size_t ws_size,
                              hipStream_t stream) {
  const float* times  = (const float*)d_in[0];
  const float* coeffs = (const float*)d_in[1];
  const float* noise  = (const float*)d_in[2];
  const float* W_init = (const float*)d_in[3];
  const float* b_init = (const float*)d_in[4];
  const float* Wf     = (const float*)d_in[5];
  const float* bf     = (const float*)d_in[6];
  const float* Wg     = (const float*)d_in[7];
  const float* bg     = (const float*)d_in[8];
  const float* W1     = (const float*)d_in[9];
  const float* b1     = (const float*)d_in[10];
  const float* W2     = (const float*)d_in[11];
  const float* b2     = (const float*)d_in[12];

  // Workspace: zhist (8.39 MB) | 8 x 128KB packed-weight slots
  char* ws = (char*)d_ws;
  _Float16* zhist = (_Float16*)(ws);
  char* wbase = ws + 8388608;
  _Float16* WfPh = (_Float16*)(wbase + 0*131072);
  _Float16* WfPl = (_Float16*)(wbase + 1*131072);
  _Float16* WgPh = (_Float16*)(wbase + 2*131072);
  _Float16* WgPl = (_Float16*)(wbase + 3*131072);
  _Float16* W1Ph = (_Float16*)(wbase + 4*131072);
  _Float16* W1Pl = (_Float16*)(wbase + 5*131072);
  _Float16* W2Ph = (_Float16*)(wbase + 6*131072);
  _Float16* W2Pl = (_Float16*)(wbase + 7*131072);

  pack_kernel<<<(H_*H_ + 255)/256, 256, 0, stream>>>(Wf, WfPh, WfPl, H_, H_);
  pack_kernel<<<(H_*H_ + 255)/256, 256, 0, stream>>>(Wg, WgPh, WgPl, H_, H_);
  pack_kernel<<<(H_*H_ + 255)/256, 256, 0, stream>>>(W1, W1Ph, W1Pl, H_, H_);
  pack_kernel<<<(H_*COUT_ + 255)/256, 256, 0, stream>>>(W2, W2Ph, W2Pl, H_, COUT_);

  scan_kernel<<<B_ / NB_, 512, 0, stream>>>(times, coeffs, noise, W_init, b_init,
                                            bf, bg, WfPh, WfPl, WgPh, WgPl, zhist);

  head_kernel<<<(B_ * OUT_T_) / 64, 256, 0, stream>>>(zhist, W1Ph, W2Ph, b1, b2,
                                                      (float*)d_out);
}